// Round 2
// baseline (8042.365 us; speedup 1.0000x reference)
//
#include <hip/hip_runtime.h>
#include <math.h>

// ---- problem dims ----
#define S_LEN 1024
#define BDIM 2
#define HDIM 8
#define DDIM 512
#define DKV 64
#define NTOK (BDIM*S_LEN)                 // 2048 rows
#define BHSD (BDIM*HDIM*S_LEN*DKV)        // 1,048,576 floats per Q/K/V tensor
#define LLAY 6

// =====================================================================
// Embedding + sinusoidal positional encoding (PE synthesized on device)
// out[token, d] = emb[seq[token], d] + PE(pos[token], d)
// =====================================================================
__global__ __launch_bounds__(256)
void embed_k(const int* __restrict__ seq, const int* __restrict__ pos,
             const float* __restrict__ emb, float* __restrict__ out)
{
    const int idx = blockIdx.x * 256 + threadIdx.x;   // float4 id, 262144 total
    const int token = idx >> 7;                       // 128 float4 per row (D=512)
    const int d4 = idx & 127;
    const int d = d4 * 4;
    const int tk = seq[token];
    const float p = (float)pos[token];
    float4 e = ((const float4*)(emb + (size_t)tk * DDIM))[d4];
    const float cst = -0.017988946038085885f;         // -ln(10000)/512
    const float f0 = expf((float)d * cst);
    const float f1 = expf((float)(d + 2) * cst);
    const float a0 = p * f0, a1 = p * f1;
    e.x += sinf(a0); e.y += cosf(a0);
    e.z += sinf(a1); e.w += cosf(a1);
    ((float4*)out)[idx] = e;
}

// =====================================================================
// Generic fp32 GEMM: C = epi(A[M,K] @ B[K,N] + bias)
// BM=BN=128, BK=16, 256 threads, 8x8 per thread. M=2048 always.
// BLAY: 0 = B row-major (ldb), 1 = QKV weight (blk,h,D,DK) layout
// EPI : 0 = plain (+bias), 1 = relu(+bias), 2 = QKV scatter (+bias, Q*0.125)
// =====================================================================
template<int BLAY, int EPI>
__global__ __launch_bounds__(256)
void gemm_k(const float* __restrict__ A, int lda,
            const float* __restrict__ B, int ldb,
            const float* __restrict__ bias,
            float* __restrict__ C, int ldc,
            int K, int which0)
{
    __shared__ float As[16][128];
    __shared__ float Bs[16][128];
    const int tid = threadIdx.x;
    const int tx = tid & 15, ty = tid >> 4;
    const int m0 = blockIdx.y * 128, n0 = blockIdx.x * 128;

    float acc[8][8];
#pragma unroll
    for (int i = 0; i < 8; ++i)
#pragma unroll
        for (int j = 0; j < 8; ++j) acc[i][j] = 0.f;

    for (int k0 = 0; k0 < K; k0 += 16) {
        // A tile 128x16 -> As transposed [k][m]
#pragma unroll
        for (int l = 0; l < 2; ++l) {
            int id = tid + l * 256;
            int r = id >> 2, c = (id & 3) * 4;
            float4 av = *(const float4*)(A + (size_t)(m0 + r) * lda + k0 + c);
            As[c + 0][r] = av.x; As[c + 1][r] = av.y;
            As[c + 2][r] = av.z; As[c + 3][r] = av.w;
        }
        // B tile 16x128 -> Bs [k][n]
#pragma unroll
        for (int l = 0; l < 2; ++l) {
            int id = tid + l * 256;
            int r = id >> 5, c = (id & 31) * 4;
            int kk = k0 + r, nn = n0 + c;
            float4 bv;
            if (BLAY == 0) bv = *(const float4*)(B + (size_t)kk * ldb + nn);
            else           bv = *(const float4*)(B + ((size_t)(nn >> 6) << 15) + (kk << 6) + (nn & 63));
            *(float4*)(&Bs[r][c]) = bv;
        }
        __syncthreads();
#pragma unroll
        for (int k = 0; k < 16; ++k) {
            float a[8], b[8];
            *(float4*)(a)     = *(const float4*)(&As[k][ty * 8]);
            *(float4*)(a + 4) = *(const float4*)(&As[k][ty * 8 + 4]);
            *(float4*)(b)     = *(const float4*)(&Bs[k][tx * 8]);
            *(float4*)(b + 4) = *(const float4*)(&Bs[k][tx * 8 + 4]);
#pragma unroll
            for (int i = 0; i < 8; ++i)
#pragma unroll
                for (int j = 0; j < 8; ++j) acc[i][j] += a[i] * b[j];
        }
        __syncthreads();
    }

    const int nb = n0 + tx * 8;
    float bb[8];
#pragma unroll
    for (int j = 0; j < 8; ++j) bb[j] = bias ? bias[nb + j] : 0.f;

    if (EPI == 2) {
        // scatter to Q/K/V tensors laid out (which, B, H, S, DK)
        const int which = which0 + (nb >> 9);
        const int h = (nb >> 6) & 7;
        const int kd = nb & 63;
        const float sc = (which == 0) ? 0.125f : 1.0f;   // 1/sqrt(64), exact pow2
#pragma unroll
        for (int i = 0; i < 8; ++i) {
            int m = m0 + ty * 8 + i;
            int b_ = m >> 10, s = m & 1023;
            float* dst = C + (size_t)which * BHSD
                       + ((size_t)(b_ * HDIM + h) * S_LEN + s) * DKV + kd;
            float v[8];
#pragma unroll
            for (int j = 0; j < 8; ++j) v[j] = (acc[i][j] + bb[j]) * sc;
            *(float4*)(dst)     = *(float4*)(v);
            *(float4*)(dst + 4) = *(float4*)(v + 4);
        }
    } else {
#pragma unroll
        for (int i = 0; i < 8; ++i) {
            int m = m0 + ty * 8 + i;
            float v[8];
#pragma unroll
            for (int j = 0; j < 8; ++j) {
                float t = acc[i][j] + bb[j];
                if (EPI == 1) t = fmaxf(t, 0.f);
                v[j] = t;
            }
            float* dst = C + (size_t)m * ldc + nb;
            *(float4*)(dst)     = *(float4*)(v);
            *(float4*)(dst + 4) = *(float4*)(v + 4);
        }
    }
}

// =====================================================================
// Flash-style fp32 attention. One block = 16 q-rows of one (b,h).
// Q pre-scaled by 1/8. Mask: pad (kv_seq[key]==0) and optional causal.
// Writes concat-head layout out[(b*S + q)*512 + h*64 + d].
// thread (q=tid/16, seg=tid%16): scores for keys {seg+16j}, output dims seg*4..+4
// =====================================================================
__global__ __launch_bounds__(256)
void flash_k(const float* __restrict__ Qm, const float* __restrict__ Km,
             const float* __restrict__ Vm, const int* __restrict__ kv_seq,
             const int causal, float* __restrict__ Out)
{
    __shared__ float Qs[16][68];
    __shared__ float Ks[64][68];
    __shared__ float Vs[64][68];
    __shared__ float Ps[16][68];
    const int tid = threadIdx.x;
    const int q = tid >> 4, seg = tid & 15;
    const int bh = blockIdx.y;
    const int b = bh >> 3, h = bh & 7;
    const int q0 = blockIdx.x * 16;
    const float* Qb = Qm + ((size_t)bh * S_LEN + q0) * DKV;
    const float* Kb = Km + (size_t)bh * S_LEN * DKV;
    const float* Vb = Vm + (size_t)bh * S_LEN * DKV;
    const int* seq = kv_seq + b * S_LEN;

    {
        // 16 rows x 64 cols: each thread writes one float4
        int r = tid >> 4, c = (tid & 15) * 4;
        *(float4*)(&Qs[r][c]) = *(const float4*)(Qb + r * DKV + c);
    }
    float m_run = -INFINITY, l_run = 0.f;
    float o0 = 0, o1 = 0, o2 = 0, o3 = 0;
    const int q_glob = q0 + q;

    for (int t = 0; t < S_LEN; t += 64) {
#pragma unroll
        for (int l = 0; l < 4; ++l) {
            int id = tid + l * 256;
            int r = id >> 4, c = (id & 15) * 4;
            *(float4*)(&Ks[r][c]) = *(const float4*)(Kb + (size_t)(t + r) * DKV + c);
            *(float4*)(&Vs[r][c]) = *(const float4*)(Vb + (size_t)(t + r) * DKV + c);
        }
        __syncthreads();

        float sc4[4] = {0, 0, 0, 0};
#pragma unroll
        for (int kk = 0; kk < 16; ++kk) {
            float4 qv = *(const float4*)(&Qs[q][kk * 4]);
#pragma unroll
            for (int j = 0; j < 4; ++j) {
                float4 kv = *(const float4*)(&Ks[seg + j * 16][kk * 4]);
                sc4[j] += qv.x * kv.x + qv.y * kv.y + qv.z * kv.z + qv.w * kv.w;
            }
        }
#pragma unroll
        for (int j = 0; j < 4; ++j) {
            int key = t + seg + j * 16;
            if (seq[key] == 0 || (causal && key > q_glob)) sc4[j] = -1.0e9f;
        }
        float tmax = fmaxf(fmaxf(sc4[0], sc4[1]), fmaxf(sc4[2], sc4[3]));
#pragma unroll
        for (int d = 8; d >= 1; d >>= 1) tmax = fmaxf(tmax, __shfl_xor(tmax, d, 16));
        const float m_new = fmaxf(m_run, tmax);
        const float corr = expf(m_run - m_new);
        float ts = 0.f, p[4];
#pragma unroll
        for (int j = 0; j < 4; ++j) { p[j] = expf(sc4[j] - m_new); ts += p[j]; }
#pragma unroll
        for (int d = 8; d >= 1; d >>= 1) ts += __shfl_xor(ts, d, 16);
        l_run = l_run * corr + ts;
        m_run = m_new;
        o0 *= corr; o1 *= corr; o2 *= corr; o3 *= corr;
#pragma unroll
        for (int j = 0; j < 4; ++j) Ps[q][seg + j * 16] = p[j];
        __syncthreads();

#pragma unroll
        for (int k4 = 0; k4 < 16; ++k4) {
            float4 p4 = *(const float4*)(&Ps[q][k4 * 4]);
            float pj[4] = {p4.x, p4.y, p4.z, p4.w};
#pragma unroll
            for (int j = 0; j < 4; ++j) {
                float4 vv = *(const float4*)(&Vs[k4 * 4 + j][seg * 4]);
                o0 += pj[j] * vv.x; o1 += pj[j] * vv.y;
                o2 += pj[j] * vv.z; o3 += pj[j] * vv.w;
            }
        }
        __syncthreads();
    }
    const float inv = 1.f / l_run;
    float4 ov = make_float4(o0 * inv, o1 * inv, o2 * inv, o3 * inv);
    *(float4*)(Out + ((size_t)(b * S_LEN + q_glob)) * DDIM + h * DKV + seg * 4) = ov;
}

// =====================================================================
// Fused residual-add + LayerNorm, in-place on x: x = LN(a + x)*g + b
// one wave per row of 512
// =====================================================================
__global__ __launch_bounds__(64)
void add_ln_k(const float* __restrict__ a, float* __restrict__ x,
              const float* __restrict__ g, const float* __restrict__ bt)
{
    const int row = blockIdx.x;
    const int lane = threadIdx.x;
    const float4* a4 = (const float4*)(a + (size_t)row * DDIM);
    float4* x4 = (float4*)(x + (size_t)row * DDIM);
    float4 va = a4[lane], vb = a4[lane + 64];
    float4 xa = x4[lane], xb = x4[lane + 64];
    float v[8] = {va.x + xa.x, va.y + xa.y, va.z + xa.z, va.w + xa.w,
                  vb.x + xb.x, vb.y + xb.y, vb.z + xb.z, vb.w + xb.w};
    float s = 0;
#pragma unroll
    for (int i = 0; i < 8; ++i) s += v[i];
#pragma unroll
    for (int d = 32; d >= 1; d >>= 1) s += __shfl_xor(s, d, 64);
    const float mu = s * (1.0f / 512.0f);
    float sq = 0;
#pragma unroll
    for (int i = 0; i < 8; ++i) { float c = v[i] - mu; sq += c * c; }
#pragma unroll
    for (int d = 32; d >= 1; d >>= 1) sq += __shfl_xor(sq, d, 64);
    const float rs = 1.0f / sqrtf(sq * (1.0f / 512.0f) + 1e-5f);
    const float4 g0 = ((const float4*)g)[lane], g1 = ((const float4*)g)[lane + 64];
    const float4 b0 = ((const float4*)bt)[lane], b1 = ((const float4*)bt)[lane + 64];
    float4 o0 = make_float4((v[0] - mu) * rs * g0.x + b0.x, (v[1] - mu) * rs * g0.y + b0.y,
                            (v[2] - mu) * rs * g0.z + b0.z, (v[3] - mu) * rs * g0.w + b0.w);
    float4 o1 = make_float4((v[4] - mu) * rs * g1.x + b1.x, (v[5] - mu) * rs * g1.y + b1.y,
                            (v[6] - mu) * rs * g1.z + b1.z, (v[7] - mu) * rs * g1.w + b1.w);
    x4[lane] = o0; x4[lane + 64] = o1;
}

// =====================================================================
extern "C" void kernel_launch(void* const* d_in, const int* in_sizes, int n_in,
                              void* d_out, int out_size, void* d_ws, size_t ws_size,
                              hipStream_t stream)
{
    const int*   src_seq        = (const int*)d_in[0];
    const int*   src_pos        = (const int*)d_in[1];
    const int*   tgt_seq        = (const int*)d_in[2];
    const int*   tgt_pos        = (const int*)d_in[3];
    const float* src_emb        = (const float*)d_in[4];
    const float* tgt_emb        = (const float*)d_in[5];
    const float* enc_attn_w     = (const float*)d_in[6];
    const float* enc_attn_b     = (const float*)d_in[7];
    const float* enc_out_w      = (const float*)d_in[8];
    const float* enc_out_b      = (const float*)d_in[9];
    const float* enc_ln         = (const float*)d_in[10];
    const float* dec_self_w     = (const float*)d_in[11];
    const float* dec_self_b     = (const float*)d_in[12];
    const float* dec_self_out_w = (const float*)d_in[13];
    const float* dec_self_out_b = (const float*)d_in[14];
    const float* dec_cross_w    = (const float*)d_in[15];
    const float* dec_cross_b    = (const float*)d_in[16];
    const float* dec_cross_out_w= (const float*)d_in[17];
    const float* dec_cross_out_b= (const float*)d_in[18];
    const float* dec_ffn_w1     = (const float*)d_in[19];
    const float* dec_ffn_b1     = (const float*)d_in[20];
    const float* dec_ffn_w2     = (const float*)d_in[21];
    const float* dec_ffn_b2     = (const float*)d_in[22];
    const float* dec_ln         = (const float*)d_in[23];
    const float* proj_w         = (const float*)d_in[24];
    float* out = (float*)d_out;

    // workspace layout (floats): 9M floats = 36 MB
    float* ws   = (float*)d_ws;
    float* xbuf = ws;                   // 1M  current stream (enc x / dec y)
    float* encb = xbuf + 1048576;       // 1M  encoder output
    float* abuf = encb + 1048576;       // 1M  attn concat out
    float* pbuf = abuf + 1048576;       // 1M  proj / ffn2 out
    float* qkv  = pbuf + 1048576;       // 3M  Q,K,V
    float* hid  = qkv  + 3 * 1048576;   // 2M  ffn hidden

    const int HDDK = HDIM * DDIM * DKV;     // 262144, one "which" slab per layer
    const dim3 blk(256);

    auto gemm_plain = [&](const float* A, int lda, const float* B, int ldb,
                          const float* bias, float* C, int ldc, int N, int K) {
        gemm_k<0, 0><<<dim3(N / 128, NTOK / 128), blk, 0, stream>>>(A, lda, B, ldb, bias, C, ldc, K, 0);
    };
    auto gemm_relu = [&](const float* A, int lda, const float* B, int ldb,
                         const float* bias, float* C, int ldc, int N, int K) {
        gemm_k<0, 1><<<dim3(N / 128, NTOK / 128), blk, 0, stream>>>(A, lda, B, ldb, bias, C, ldc, K, 0);
    };
    auto gemm_qkv = [&](const float* A, const float* W, const float* bias,
                        int which0, int N) {
        gemm_k<1, 2><<<dim3(N / 128, NTOK / 128), blk, 0, stream>>>(A, DDIM, W, 0, bias, qkv, 0, DDIM, which0);
    };
    auto flash = [&](const int* kvseq, int causal) {
        flash_k<<<dim3(S_LEN / 16, BDIM * HDIM), blk, 0, stream>>>(
            qkv, qkv + BHSD, qkv + 2 * BHSD, kvseq, causal, abuf);
    };
    auto add_ln = [&](const float* a, float* x, const float* gamma, const float* beta) {
        add_ln_k<<<dim3(NTOK), dim3(64), 0, stream>>>(a, x, gamma, beta);
    };

    // ---------------- encoder ----------------
    embed_k<<<dim3(NTOK * DDIM / 4 / 256), blk, 0, stream>>>(src_seq, src_pos, src_emb, xbuf);
    for (int i = 0; i < LLAY; ++i) {
        gemm_qkv(xbuf, enc_attn_w + (size_t)i * 3 * HDDK, enc_attn_b + i * 1536, 0, 1536);
        flash(src_seq, 0);
        gemm_plain(abuf, DDIM, enc_out_w + (size_t)i * DDIM * DDIM, DDIM,
                   enc_out_b + i * DDIM, pbuf, DDIM, DDIM, DDIM);
        add_ln(pbuf, xbuf, enc_ln + i * 2 * DDIM, enc_ln + i * 2 * DDIM + DDIM);
    }
    hipMemcpyAsync(encb, xbuf, (size_t)NTOK * DDIM * sizeof(float),
                   hipMemcpyDeviceToDevice, stream);

    // ---------------- decoder ----------------
    embed_k<<<dim3(NTOK * DDIM / 4 / 256), blk, 0, stream>>>(tgt_seq, tgt_pos, tgt_emb, xbuf);
    for (int i = 0; i < LLAY; ++i) {
        // self-attention (causal + tgt pad)
        gemm_qkv(xbuf, dec_self_w + (size_t)i * 3 * HDDK, dec_self_b + i * 1536, 0, 1536);
        flash(tgt_seq, 1);
        gemm_plain(abuf, DDIM, dec_self_out_w + (size_t)i * DDIM * DDIM, DDIM,
                   dec_self_out_b + i * DDIM, pbuf, DDIM, DDIM, DDIM);
        add_ln(pbuf, xbuf, dec_ln + i * 3072, dec_ln + i * 3072 + 512);

        // cross-attention: Q from y, K/V from encoder output (src pad mask)
        gemm_qkv(xbuf, dec_cross_w + (size_t)i * 3 * HDDK, dec_cross_b + i * 1536, 0, 512);
        gemm_qkv(encb, dec_cross_w + (size_t)i * 3 * HDDK + HDDK, dec_cross_b + i * 1536 + 512, 1, 1024);
        flash(src_seq, 0);
        gemm_plain(abuf, DDIM, dec_cross_out_w + (size_t)i * DDIM * DDIM, DDIM,
                   dec_cross_out_b + i * DDIM, pbuf, DDIM, DDIM, DDIM);
        add_ln(pbuf, xbuf, dec_ln + i * 3072 + 1024, dec_ln + i * 3072 + 1536);

        // FFN
        gemm_relu(xbuf, DDIM, dec_ffn_w1 + (size_t)i * DDIM * 1024, 1024,
                  dec_ffn_b1 + i * 1024, hid, 1024, 1024, DDIM);
        gemm_plain(hid, 1024, dec_ffn_w2 + (size_t)i * 1024 * DDIM, DDIM,
                   dec_ffn_b2 + i * DDIM, pbuf, DDIM, DDIM, 1024);
        add_ln(pbuf, xbuf, dec_ln + i * 3072 + 2048, dec_ln + i * 3072 + 2560);
    }

    // ---------------- final projection (no bias) ----------------
    gemm_plain(xbuf, DDIM, proj_w, 32000, nullptr, out, 32000, 32000, DDIM);
}

// Round 3
// 4133.091 us; speedup vs baseline: 1.9458x; 1.9458x over previous
//
#include <hip/hip_runtime.h>
#include <math.h>

// ---- problem dims ----
#define S_LEN 1024
#define BDIM 2
#define HDIM 8
#define DDIM 512
#define DKV 64
#define NTOK (BDIM*S_LEN)                 // 2048 rows
#define BHSD (BDIM*HDIM*S_LEN*DKV)        // 1,048,576 floats per Q/K/V tensor
#define LLAY 6

typedef __attribute__((ext_vector_type(8))) short short8;
typedef __attribute__((ext_vector_type(4))) float f32x4;

// fp32 -> bf16 round-to-nearest-even (finite inputs)
__device__ __forceinline__ unsigned short f2b(float f) {
    unsigned u = __float_as_uint(f);
    unsigned r = (u + 0x7FFFu + ((u >> 16) & 1u)) >> 16;
    return (unsigned short)r;
}
__device__ __forceinline__ unsigned pack2(float a, float b) {
    return (unsigned)f2b(a) | ((unsigned)f2b(b) << 16);
}

// =====================================================================
// Batched transpose-cast: in fp32 [B][R][C] -> out bf16 [B][C][R]
// grid (C/32, R/32, B), 256 threads
// =====================================================================
__global__ __launch_bounds__(256)
void tcast_k(const float* __restrict__ in, unsigned short* __restrict__ out,
             int R, int C)
{
    __shared__ float t[32][33];
    const int tid = threadIdx.x;
    const int lr = tid & 31, lw = tid >> 5;            // lw 0..7
    const size_t base = (size_t)blockIdx.z * R * C;
    const int r0 = blockIdx.y * 32, c0 = blockIdx.x * 32;
#pragma unroll
    for (int j = 0; j < 4; ++j)
        t[lw + j * 8][lr] = in[base + (size_t)(r0 + lw + j * 8) * C + c0 + lr];
    __syncthreads();
#pragma unroll
    for (int j = 0; j < 4; ++j)
        out[base + (size_t)(c0 + lw + j * 8) * R + r0 + lr] = f2b(t[lr][lw + j * 8]);
}

// =====================================================================
// Embedding + sinusoidal PE -> fp32 (residual) + bf16 (GEMM input)
// =====================================================================
__global__ __launch_bounds__(256)
void embed_k(const int* __restrict__ seq, const int* __restrict__ pos,
             const float* __restrict__ emb, float* __restrict__ out,
             unsigned short* __restrict__ out16)
{
    const int idx = blockIdx.x * 256 + threadIdx.x;   // float4 id, 524288 total
    const int token = idx >> 7;                       // 128 float4 per row (D=512)
    const int d4 = idx & 127;
    const int d = d4 * 4;
    const int tk = seq[token];
    const float p = (float)pos[token];
    float4 e = ((const float4*)(emb + (size_t)tk * DDIM))[d4];
    const float cst = -0.017988946038085885f;         // -ln(10000)/512
    const float f0 = expf((float)d * cst);
    const float f1 = expf((float)(d + 2) * cst);
    const float a0 = p * f0, a1 = p * f1;
    e.x += sinf(a0); e.y += cosf(a0);
    e.z += sinf(a1); e.w += cosf(a1);
    ((float4*)out)[idx] = e;
    uint2 b; b.x = pack2(e.x, e.y); b.y = pack2(e.z, e.w);
    *(uint2*)(out16 + (size_t)idx * 4) = b;
}

// =====================================================================
// MFMA bf16 GEMM: C = epi(A[M,K]bf16 @ Bt[N,K]bf16^T + bias)
// BM=BN=128, BK=64, 256 thr = 4 waves (2x2), wave tile 64x64 = 4x4 frags
// EPI: 0 = fp32 out (+bias), 1 = relu -> bf16 out, 2 = QKV fp32 scatter
// =====================================================================
template<int EPI>
__global__ __launch_bounds__(256)
void mgemm_k(const unsigned short* __restrict__ A,
             const unsigned short* __restrict__ Bt,
             const float* __restrict__ bias,
             void* __restrict__ Cout,
             int K, int ldc, int which0)
{
    __shared__ unsigned short As[128 * 72];   // 64 k + 8 pad per row
    __shared__ unsigned short Bs[128 * 72];
    const int tid = threadIdx.x;
    const int lane = tid & 63, w = tid >> 6;
    const int wr = w >> 1, wc = w & 1;
    const int r15 = lane & 15, khalf = lane >> 4;     // khalf 0..3
    const int m0 = blockIdx.y * 128, n0 = blockIdx.x * 128;

    f32x4 acc[4][4];
#pragma unroll
    for (int m = 0; m < 4; ++m)
#pragma unroll
        for (int n = 0; n < 4; ++n) acc[m][n] = (f32x4)0.f;

    for (int k0 = 0; k0 < K; k0 += 64) {
#pragma unroll
        for (int l = 0; l < 4; ++l) {
            int id = tid + l * 256;
            int r = id >> 3, s = id & 7;
            int4 va = *(const int4*)(A  + (size_t)(m0 + r) * K + k0 + s * 8);
            int4 vb = *(const int4*)(Bt + (size_t)(n0 + r) * K + k0 + s * 8);
            *(int4*)(&As[r * 72 + s * 8]) = va;
            *(int4*)(&Bs[r * 72 + s * 8]) = vb;
        }
        __syncthreads();
#pragma unroll
        for (int kk = 0; kk < 2; ++kk) {
            short8 aF[4], bF[4];
#pragma unroll
            for (int m = 0; m < 4; ++m)
                aF[m] = *(const short8*)(&As[(wr * 64 + m * 16 + r15) * 72 + kk * 32 + khalf * 8]);
#pragma unroll
            for (int n = 0; n < 4; ++n)
                bF[n] = *(const short8*)(&Bs[(wc * 64 + n * 16 + r15) * 72 + kk * 32 + khalf * 8]);
#pragma unroll
            for (int m = 0; m < 4; ++m)
#pragma unroll
                for (int n = 0; n < 4; ++n)
                    acc[m][n] = __builtin_amdgcn_mfma_f32_16x16x32_bf16(aF[m], bF[n], acc[m][n], 0, 0, 0);
        }
        __syncthreads();
    }

#pragma unroll
    for (int n = 0; n < 4; ++n) {
        const int col = n0 + wc * 64 + n * 16 + r15;
        const float bval = bias ? bias[col] : 0.f;
#pragma unroll
        for (int m = 0; m < 4; ++m) {
#pragma unroll
            for (int j = 0; j < 4; ++j) {
                const int row = m0 + wr * 64 + m * 16 + khalf * 4 + j;
                float v = acc[m][n][j] + bval;
                if (EPI == 0) {
                    ((float*)Cout)[(size_t)row * ldc + col] = v;
                } else if (EPI == 1) {
                    ((unsigned short*)Cout)[(size_t)row * ldc + col] = f2b(fmaxf(v, 0.f));
                } else {
                    const int which = which0 + (col >> 9);
                    const int h = (col >> 6) & 7, kd = col & 63;
                    const int b_ = row >> 10, s = row & 1023;
                    const float sc = (which == 0) ? 0.125f : 1.0f;
                    ((float*)Cout)[(size_t)which * BHSD +
                                   ((size_t)(b_ * HDIM + h) * S_LEN + s) * DKV + kd] = v * sc;
                }
            }
        }
    }
}

// =====================================================================
// Flash-style fp32 attention (validated). Writes bf16 concat-head out.
// =====================================================================
__global__ __launch_bounds__(256)
void flash_k(const float* __restrict__ Qm, const float* __restrict__ Km,
             const float* __restrict__ Vm, const int* __restrict__ kv_seq,
             const int causal, unsigned short* __restrict__ Out)
{
    __shared__ float Qs[16][68];
    __shared__ float Ks[64][68];
    __shared__ float Vs[64][68];
    __shared__ float Ps[16][68];
    const int tid = threadIdx.x;
    const int q = tid >> 4, seg = tid & 15;
    const int bh = blockIdx.y;
    const int b = bh >> 3, h = bh & 7;
    const int q0 = blockIdx.x * 16;
    const float* Qb = Qm + ((size_t)bh * S_LEN + q0) * DKV;
    const float* Kb = Km + (size_t)bh * S_LEN * DKV;
    const float* Vb = Vm + (size_t)bh * S_LEN * DKV;
    const int* seq = kv_seq + b * S_LEN;

    {
        int r = tid >> 4, c = (tid & 15) * 4;
        *(float4*)(&Qs[r][c]) = *(const float4*)(Qb + r * DKV + c);
    }
    float m_run = -INFINITY, l_run = 0.f;
    float o0 = 0, o1 = 0, o2 = 0, o3 = 0;
    const int q_glob = q0 + q;

    for (int t = 0; t < S_LEN; t += 64) {
#pragma unroll
        for (int l = 0; l < 4; ++l) {
            int id = tid + l * 256;
            int r = id >> 4, c = (id & 15) * 4;
            *(float4*)(&Ks[r][c]) = *(const float4*)(Kb + (size_t)(t + r) * DKV + c);
            *(float4*)(&Vs[r][c]) = *(const float4*)(Vb + (size_t)(t + r) * DKV + c);
        }
        __syncthreads();

        float sc4[4] = {0, 0, 0, 0};
#pragma unroll
        for (int kk = 0; kk < 16; ++kk) {
            float4 qv = *(const float4*)(&Qs[q][kk * 4]);
#pragma unroll
            for (int j = 0; j < 4; ++j) {
                float4 kv = *(const float4*)(&Ks[seg + j * 16][kk * 4]);
                sc4[j] += qv.x * kv.x + qv.y * kv.y + qv.z * kv.z + qv.w * kv.w;
            }
        }
#pragma unroll
        for (int j = 0; j < 4; ++j) {
            int key = t + seg + j * 16;
            if (seq[key] == 0 || (causal && key > q_glob)) sc4[j] = -1.0e9f;
        }
        float tmax = fmaxf(fmaxf(sc4[0], sc4[1]), fmaxf(sc4[2], sc4[3]));
#pragma unroll
        for (int d = 8; d >= 1; d >>= 1) tmax = fmaxf(tmax, __shfl_xor(tmax, d, 16));
        const float m_new = fmaxf(m_run, tmax);
        const float corr = expf(m_run - m_new);
        float ts = 0.f, p[4];
#pragma unroll
        for (int j = 0; j < 4; ++j) { p[j] = expf(sc4[j] - m_new); ts += p[j]; }
#pragma unroll
        for (int d = 8; d >= 1; d >>= 1) ts += __shfl_xor(ts, d, 16);
        l_run = l_run * corr + ts;
        m_run = m_new;
        o0 *= corr; o1 *= corr; o2 *= corr; o3 *= corr;
#pragma unroll
        for (int j = 0; j < 4; ++j) Ps[q][seg + j * 16] = p[j];
        __syncthreads();

#pragma unroll
        for (int k4 = 0; k4 < 16; ++k4) {
            float4 p4 = *(const float4*)(&Ps[q][k4 * 4]);
            float pj[4] = {p4.x, p4.y, p4.z, p4.w};
#pragma unroll
            for (int j = 0; j < 4; ++j) {
                float4 vv = *(const float4*)(&Vs[k4 * 4 + j][seg * 4]);
                o0 += pj[j] * vv.x; o1 += pj[j] * vv.y;
                o2 += pj[j] * vv.z; o3 += pj[j] * vv.w;
            }
        }
        __syncthreads();
    }
    const float inv = 1.f / l_run;
    uint2 ov;
    ov.x = pack2(o0 * inv, o1 * inv);
    ov.y = pack2(o2 * inv, o3 * inv);
    *(uint2*)(Out + ((size_t)(b * S_LEN + q_glob)) * DDIM + h * DKV + seg * 4) = ov;
}

// =====================================================================
// Fused residual-add + LayerNorm: x = LN(a + x)*g + b (fp32) + bf16 copy
// =====================================================================
__global__ __launch_bounds__(64)
void add_ln_k(const float* __restrict__ a, float* __restrict__ x,
              unsigned short* __restrict__ x16,
              const float* __restrict__ g, const float* __restrict__ bt)
{
    const int row = blockIdx.x;
    const int lane = threadIdx.x;
    const float4* a4 = (const float4*)(a + (size_t)row * DDIM);
    float4* x4 = (float4*)(x + (size_t)row * DDIM);
    float4 va = a4[lane], vb = a4[lane + 64];
    float4 xa = x4[lane], xb = x4[lane + 64];
    float v[8] = {va.x + xa.x, va.y + xa.y, va.z + xa.z, va.w + xa.w,
                  vb.x + xb.x, vb.y + xb.y, vb.z + xb.z, vb.w + xb.w};
    float s = 0;
#pragma unroll
    for (int i = 0; i < 8; ++i) s += v[i];
#pragma unroll
    for (int d = 32; d >= 1; d >>= 1) s += __shfl_xor(s, d, 64);
    const float mu = s * (1.0f / 512.0f);
    float sq = 0;
#pragma unroll
    for (int i = 0; i < 8; ++i) { float c = v[i] - mu; sq += c * c; }
#pragma unroll
    for (int d = 32; d >= 1; d >>= 1) sq += __shfl_xor(sq, d, 64);
    const float rs = 1.0f / sqrtf(sq * (1.0f / 512.0f) + 1e-5f);
    const float4 g0 = ((const float4*)g)[lane], g1 = ((const float4*)g)[lane + 64];
    const float4 b0 = ((const float4*)bt)[lane], b1 = ((const float4*)bt)[lane + 64];
    float4 o0 = make_float4((v[0] - mu) * rs * g0.x + b0.x, (v[1] - mu) * rs * g0.y + b0.y,
                            (v[2] - mu) * rs * g0.z + b0.z, (v[3] - mu) * rs * g0.w + b0.w);
    float4 o1 = make_float4((v[4] - mu) * rs * g1.x + b1.x, (v[5] - mu) * rs * g1.y + b1.y,
                            (v[6] - mu) * rs * g1.z + b1.z, (v[7] - mu) * rs * g1.w + b1.w);
    x4[lane] = o0; x4[lane + 64] = o1;
    uint2 p0; p0.x = pack2(o0.x, o0.y); p0.y = pack2(o0.z, o0.w);
    uint2 p1; p1.x = pack2(o1.x, o1.y); p1.y = pack2(o1.z, o1.w);
    *(uint2*)(x16 + (size_t)row * DDIM + lane * 4) = p0;
    *(uint2*)(x16 + (size_t)row * DDIM + 256 + lane * 4) = p1;
}

// =====================================================================
extern "C" void kernel_launch(void* const* d_in, const int* in_sizes, int n_in,
                              void* d_out, int out_size, void* d_ws, size_t ws_size,
                              hipStream_t stream)
{
    const int*   src_seq        = (const int*)d_in[0];
    const int*   src_pos        = (const int*)d_in[1];
    const int*   tgt_seq        = (const int*)d_in[2];
    const int*   tgt_pos        = (const int*)d_in[3];
    const float* src_emb        = (const float*)d_in[4];
    const float* tgt_emb        = (const float*)d_in[5];
    const float* enc_attn_w     = (const float*)d_in[6];
    const float* enc_attn_b     = (const float*)d_in[7];
    const float* enc_out_w      = (const float*)d_in[8];
    const float* enc_out_b      = (const float*)d_in[9];
    const float* enc_ln         = (const float*)d_in[10];
    const float* dec_self_w     = (const float*)d_in[11];
    const float* dec_self_b     = (const float*)d_in[12];
    const float* dec_self_out_w = (const float*)d_in[13];
    const float* dec_self_out_b = (const float*)d_in[14];
    const float* dec_cross_w    = (const float*)d_in[15];
    const float* dec_cross_b    = (const float*)d_in[16];
    const float* dec_cross_out_w= (const float*)d_in[17];
    const float* dec_cross_out_b= (const float*)d_in[18];
    const float* dec_ffn_w1     = (const float*)d_in[19];
    const float* dec_ffn_b1     = (const float*)d_in[20];
    const float* dec_ffn_w2     = (const float*)d_in[21];
    const float* dec_ffn_b2     = (const float*)d_in[22];
    const float* dec_ln         = (const float*)d_in[23];
    const float* proj_w         = (const float*)d_in[24];
    float* out = (float*)d_out;

    // ---------------- workspace layout ----------------
    float* ws   = (float*)d_ws;
    float* xbuf = ws;                   // 1M f32 residual stream
    float* pbuf = xbuf + 1048576;       // 1M f32 pre-LN GEMM out
    float* qkv  = pbuf + 1048576;       // 3M f32 Q,K,V
    unsigned short* u16 = (unsigned short*)(qkv + 3 * 1048576);
    unsigned short* xb16   = u16;                  // 1M bf16
    unsigned short* encb16 = xb16 + 1048576;       // 1M
    unsigned short* ab16   = encb16 + 1048576;     // 1M  attn out
    unsigned short* hid16  = ab16 + 1048576;       // 2M  ffn hidden
    unsigned short* wp = hid16 + 2 * 1048576;
    // transposed bf16 weights
    unsigned short* wEncA  = wp;                wp += (size_t)LLAY * 786432;
    unsigned short* wEncO  = wp;                wp += (size_t)LLAY * 262144;
    unsigned short* wSelfA = wp;                wp += (size_t)LLAY * 786432;
    unsigned short* wSelfO = wp;                wp += (size_t)LLAY * 262144;
    unsigned short* wCrossA= wp;                wp += (size_t)LLAY * 786432;
    unsigned short* wCrossO= wp;                wp += (size_t)LLAY * 262144;
    unsigned short* w1t    = wp;                wp += (size_t)LLAY * 524288;
    unsigned short* w2t    = wp;                wp += (size_t)LLAY * 524288;
    unsigned short* wPt    = wp;

    const dim3 blk(256);

    // ---------------- weight transpose-casts ----------------
    tcast_k<<<dim3(2, 16, 144), blk, 0, stream>>>(enc_attn_w, wEncA, 512, 64);
    tcast_k<<<dim3(16, 16, 6),  blk, 0, stream>>>(enc_out_w, wEncO, 512, 512);
    tcast_k<<<dim3(2, 16, 144), blk, 0, stream>>>(dec_self_w, wSelfA, 512, 64);
    tcast_k<<<dim3(16, 16, 6),  blk, 0, stream>>>(dec_self_out_w, wSelfO, 512, 512);
    tcast_k<<<dim3(2, 16, 144), blk, 0, stream>>>(dec_cross_w, wCrossA, 512, 64);
    tcast_k<<<dim3(16, 16, 6),  blk, 0, stream>>>(dec_cross_out_w, wCrossO, 512, 512);
    tcast_k<<<dim3(32, 16, 6),  blk, 0, stream>>>(dec_ffn_w1, w1t, 512, 1024);
    tcast_k<<<dim3(16, 32, 6),  blk, 0, stream>>>(dec_ffn_w2, w2t, 1024, 512);
    tcast_k<<<dim3(1000, 16, 1),blk, 0, stream>>>(proj_w, wPt, 512, 32000);

    auto gemm0 = [&](const unsigned short* A, const unsigned short* Bt,
                     const float* bias, float* C, int N, int K) {
        mgemm_k<0><<<dim3(N / 128, NTOK / 128), blk, 0, stream>>>(A, Bt, bias, C, K, N, 0);
    };
    auto gemm1 = [&](const unsigned short* A, const unsigned short* Bt,
                     const float* bias, unsigned short* C, int N, int K) {
        mgemm_k<1><<<dim3(N / 128, NTOK / 128), blk, 0, stream>>>(A, Bt, bias, C, K, N, 0);
    };
    auto gemm2 = [&](const unsigned short* A, const unsigned short* Bt,
                     const float* bias, int N, int which0) {
        mgemm_k<2><<<dim3(N / 128, NTOK / 128), blk, 0, stream>>>(A, Bt, bias, qkv, 512, 0, which0);
    };
    auto flash = [&](const int* kvseq, int causal) {
        flash_k<<<dim3(S_LEN / 16, BDIM * HDIM), blk, 0, stream>>>(
            qkv, qkv + BHSD, qkv + 2 * BHSD, kvseq, causal, ab16);
    };
    auto add_ln = [&](const float* a, const float* gamma, const float* beta) {
        add_ln_k<<<dim3(NTOK), dim3(64), 0, stream>>>(a, xbuf, xb16, gamma, beta);
    };

    // ---------------- encoder ----------------
    embed_k<<<dim3(NTOK * DDIM / 4 / 256), blk, 0, stream>>>(src_seq, src_pos, src_emb, xbuf, xb16);
    for (int i = 0; i < LLAY; ++i) {
        gemm2(xb16, wEncA + (size_t)i * 786432, enc_attn_b + i * 1536, 1536, 0);
        flash(src_seq, 0);
        gemm0(ab16, wEncO + (size_t)i * 262144, enc_out_b + i * 512, pbuf, 512, 512);
        add_ln(pbuf, enc_ln + i * 1024, enc_ln + i * 1024 + 512);
    }
    hipMemcpyAsync(encb16, xb16, (size_t)NTOK * DDIM * sizeof(unsigned short),
                   hipMemcpyDeviceToDevice, stream);

    // ---------------- decoder ----------------
    embed_k<<<dim3(NTOK * DDIM / 4 / 256), blk, 0, stream>>>(tgt_seq, tgt_pos, tgt_emb, xbuf, xb16);
    for (int i = 0; i < LLAY; ++i) {
        // self-attention (causal + tgt pad)
        gemm2(xb16, wSelfA + (size_t)i * 786432, dec_self_b + i * 1536, 1536, 0);
        flash(tgt_seq, 1);
        gemm0(ab16, wSelfO + (size_t)i * 262144, dec_self_out_b + i * 512, pbuf, 512, 512);
        add_ln(pbuf, dec_ln + i * 3072, dec_ln + i * 3072 + 512);

        // cross-attention: Q from y, K/V from encoder output
        gemm2(xb16, wCrossA + (size_t)i * 786432, dec_cross_b + i * 1536, 512, 0);
        gemm2(encb16, wCrossA + (size_t)i * 786432 + 262144, dec_cross_b + i * 1536 + 512, 1024, 1);
        flash(src_seq, 0);
        gemm0(ab16, wCrossO + (size_t)i * 262144, dec_cross_out_b + i * 512, pbuf, 512, 512);
        add_ln(pbuf, dec_ln + i * 3072 + 1024, dec_ln + i * 3072 + 1536);

        // FFN
        gemm1(xb16, w1t + (size_t)i * 524288, dec_ffn_b1 + i * 1024, hid16, 1024, 512);
        gemm0(hid16, w2t + (size_t)i * 524288, dec_ffn_b2 + i * 512, pbuf, 512, 1024);
        add_ln(pbuf, dec_ln + i * 3072 + 2048, dec_ln + i * 3072 + 2560);
    }

    // ---------------- final projection (no bias) ----------------
    gemm0(xb16, wPt, nullptr, out, 32000, 512);
}